// Round 10
// baseline (862.129 us; speedup 1.0000x reference)
//
#include <hip/hip_runtime.h>
#include <hip/hip_bf16.h>
#include <stdint.h>

// T=1, B=64, C=E=512, H=W=8, NH=8, HD=64, TOT=4096, MEM=32, FF=2048
typedef __attribute__((ext_vector_type(8))) short bf16x8;
typedef __attribute__((ext_vector_type(4))) float f32x4;

static __device__ __forceinline__ unsigned short f2bf(float f) {
  union { float f; unsigned int u; } v; v.f = f;
  unsigned int u = v.u;
  return (unsigned short)((u + 0x7FFFu + ((u >> 16) & 1u)) >> 16);
}

static __device__ __forceinline__ void gld16(const void* g, void* l) {
  __builtin_amdgcn_global_load_lds(
      (const __attribute__((address_space(1))) unsigned int*)g,
      (__attribute__((address_space(3))) unsigned int*)l, 16, 0, 0);
}

// ---------- merged: border-zero of 4 padded buffers + 4x weight transform + input pad ----------
__global__ __launch_bounds__(256) void k_prep(
    const float* __restrict__ projw, const float* __restrict__ outw,
    const float* __restrict__ l1w, const float* __restrict__ l2w,
    const float* __restrict__ x,
    unsigned short* __restrict__ wbP, unsigned short* __restrict__ wbO,
    unsigned short* __restrict__ wbL1, unsigned short* __restrict__ wbL2,
    unsigned short* __restrict__ xp, unsigned short* __restrict__ apad,
    unsigned short* __restrict__ l1pad, unsigned short* __restrict__ ffpad) {
  int bid = blockIdx.x, t = threadIdx.x;
  if (bid < 9216) {
    int buf = bid / 2304, rem = bid - buf * 2304;
    int b = rem / 36, ridx = rem - b * 36;
    int row;
    if (ridx < 11) row = ridx;
    else if (ridx < 25) { int p = ridx - 11; row = 19 + (p >> 1) * 10 + (p & 1); }
    else row = 89 + (ridx - 25);
    unsigned short* ptr; int C;
    switch (buf) {
      case 0: ptr = xp;    C = 512;  break;
      case 1: ptr = apad;  C = 512;  break;
      case 2: ptr = l1pad; C = 512;  break;
      default: ptr = ffpad; C = 2048; break;
    }
    int n16 = C >> 3;
    if (t < n16) *(uint4*)(ptr + ((size_t)b * 100 + row) * C + t * 8) = make_uint4(0u, 0u, 0u, 0u);
    return;
  }
  __shared__ float l[4608];
  int id = bid - 9216;
  if (id < 6144) {
    const float* in; unsigned short* out; int o, C, c0;
    if (id < 1536)      { in = projw; out = wbP;  o = id;               C = 512;  c0 = 0; }
    else if (id < 2048) { in = outw;  out = wbO;  o = id - 1536;        C = 512;  c0 = 0; }
    else if (id < 4096) { in = l1w;   out = wbL1; o = id - 2048;        C = 512;  c0 = 0; }
    else                { in = l2w;   out = wbL2; o = (id - 4096) >> 2; C = 2048; c0 = ((id - 4096) & 3) << 9; }
    const float* src = in + ((size_t)o * C + c0) * 9;
    for (int j = t; j < 4608; j += 256) l[j] = src[j];
    __syncthreads();
    unsigned short* dst = out + (size_t)o * 9 * C;
#pragma unroll
    for (int j = 0; j < 18; ++j) {
      int f = t * 18 + j;
      int tap = f >> 9, c = f & 511;
      dst[(size_t)tap * C + c0 + c] = f2bf(l[c * 9 + tap]);
    }
  } else {
    int idx = id - 6144;
    int b = idx >> 3, c0 = (idx & 7) << 6;
    float (*lt)[65] = (float(*)[65])l;
    int cr = t >> 2, p0 = (t & 3) << 4;
    const float* src = x + ((size_t)b * 512 + c0 + cr) * 64 + p0;
#pragma unroll
    for (int j = 0; j < 4; ++j) {
      float4 v = *(const float4*)(src + j * 4);
      lt[cr][p0 + j * 4 + 0] = v.x; lt[cr][p0 + j * 4 + 1] = v.y;
      lt[cr][p0 + j * 4 + 2] = v.z; lt[cr][p0 + j * 4 + 3] = v.w;
    }
    __syncthreads();
    int pix = t >> 2, cc0 = (t & 3) << 4;
    size_t prow = (size_t)b * 100 + 11 + (pix >> 3) * 10 + (pix & 7);
    unsigned short pk[16];
#pragma unroll
    for (int j = 0; j < 16; ++j) pk[j] = f2bf(lt[cc0 + j][pix]);
    *(uint4*)(xp + prow * 512 + c0 + cc0) = *(const uint4*)pk;
    *(uint4*)(xp + prow * 512 + c0 + cc0 + 8) = *(const uint4*)(pk + 8);
  }
}

// ---------- tap-shifted conv GEMM, double-buffered, with optional woven bulk-copy ----------
// Weave: when wdst != nullptr, at K-step kt<31 each block loads one 16 KB unit
// (u = kt*512 + flat, flat in [0,512)) of wsrc(+wpw) into regs, stores it next step.
// EPI: 0 = +bias fp32 NCHW; 3 = raw partial fp32 NCHW; 4 = +bias+relu bf16 NHWC-padded
template <int EPI>
__global__ __launch_bounds__(256, 2) void k_gemm9(
    const unsigned short* __restrict__ Wt, int ldK,
    const unsigned short* __restrict__ Xp, int C, int tlog,
    int kiter, const float* __restrict__ bias,
    void* __restrict__ outv, int Cout, size_t zstride,
    const float* __restrict__ wsrc, const float* __restrict__ wpw,
    float* __restrict__ wdst) {
  __shared__ unsigned short lds[2][2][8192];
  int t = threadIdx.x, lane = t & 63, wid = t >> 6;

  int gx = gridDim.x;
  int f = blockIdx.x + blockIdx.y * gx;
  int cpx = (gx * gridDim.y) >> 3;
  int fs = (f & 7) * cpx + (f >> 3);
  int bx = fs % gx, by = fs / gx;

  int O0 = bx << 7, M0 = by << 7;
  int kbase = blockIdx.z * kiter;
  int srow = lane >> 3, skg = (lane & 7) << 3;

  int wrow[4], pbv[4];
#pragma unroll
  for (int i = 0; i < 4; ++i) {
    int rl = wid * 8 + i * 32 + srow;
    wrow[i] = O0 + rl;
    int m = M0 + rl, b = m >> 6, pix = m & 63;
    pbv[i] = b * 100 + (pix >> 3) * 10 + (pix & 7);
  }

  f32x4 acc[4][4];
#pragma unroll
  for (int i = 0; i < 4; ++i)
#pragma unroll
    for (int j = 0; j < 4; ++j) acc[i][j] = (f32x4){0.f, 0.f, 0.f, 0.f};

  auto stage = [&](int buf, int kt) {
    int gk = kbase + kt;
    int tap = gk >> tlog;
    int c0 = (gk - (tap << tlog)) << 6;
    int toff = tap + 7 * ((tap * 11) >> 5);  // ky*10+kx
#pragma unroll
    for (int i = 0; i < 4; ++i) {
      gld16(Wt + (size_t)wrow[i] * ldK + (gk << 6) + skg,
            &lds[buf][0][(wid * 8 + i * 32) * 64]);
      gld16(Xp + (size_t)(pbv[i] + toff) * C + c0 + skg,
            &lds[buf][1][(wid * 8 + i * 32) * 64]);
    }
  };

  int wr = wid >> 1, wc = wid & 1;
  int frow = lane & 15, fkb = (lane >> 4) << 3;

  auto compute = [&](int buf) {
    const unsigned short* Wl = &lds[buf][0][0];
    const unsigned short* Xl = &lds[buf][1][0];
#pragma unroll
    for (int kk = 0; kk < 2; ++kk) {
      bf16x8 af[4], bfv[4];
#pragma unroll
      for (int ff = 0; ff < 4; ++ff) {
        af[ff]  = *(const bf16x8*)(Wl + ((wr * 64 + ff * 16 + frow) << 6) + kk * 32 + fkb);
        bfv[ff] = *(const bf16x8*)(Xl + ((wc * 64 + ff * 16 + frow) << 6) + kk * 32 + fkb);
      }
#pragma unroll
      for (int fi = 0; fi < 4; ++fi)
#pragma unroll
        for (int fj = 0; fj < 4; ++fj)
          acc[fi][fj] = __builtin_amdgcn_mfma_f32_16x16x32_bf16(af[fi], bfv[fj], acc[fi][fj], 0, 0, 0);
    }
  };

  // weave state
  int flat = blockIdx.x + gx * (blockIdx.y + (blockIdx.z << 5));
  float4 cb[4];
  float* wd = nullptr;

  stage(0, 0);
  __syncthreads();
  for (int kt = 0; kt < kiter; ++kt) {
    int cur = kt & 1;
    if (kt + 1 < kiter) stage(cur ^ 1, kt + 1);
    if (wdst) {
      if (wd) {  // store unit loaded last step
        *(float4*)(wd + 0)  = cb[0];
        *(float4*)(wd + 4)  = cb[1];
        *(float4*)(wd + 8)  = cb[2];
        *(float4*)(wd + 12) = cb[3];
        wd = nullptr;
      }
      if (kt < 31) {  // load unit kt*512+flat
        int u = kt * 512 + flat;
        int b = u / 248;
        int rem = u - b * 248;
        int m = rem >> 3, h = rem & 7;
        const float* src = wsrc + (((size_t)(b * 32 + m + 1) * 8 + h) << 12) + t * 16;
        wd = wdst + (((size_t)(b * 32 + m) * 8 + h) << 12) + t * 16;
        if (wpw) {
          const float* pp = wpw + ((size_t)m << 15) + (h << 12) + t * 16;
#pragma unroll
          for (int j = 0; j < 4; ++j) {
            float4 a = *(const float4*)(src + j * 4);
            float4 p = *(const float4*)(pp + j * 4);
            cb[j] = make_float4(a.x + p.x, a.y + p.y, a.z + p.z, a.w + p.w);
          }
        } else {
#pragma unroll
          for (int j = 0; j < 4; ++j) cb[j] = *(const float4*)(src + j * 4);
        }
      }
    }
    compute(cur);
    __syncthreads();
  }

  int ob = O0 + wr * 64, mb = M0 + wc * 64;
  int r0 = (lane >> 4) << 2, cm = lane & 15;
  if (EPI == 4) {
    unsigned short* outp = (unsigned short*)outv;
#pragma unroll
    for (int fi = 0; fi < 4; ++fi) {
      int oo = ob + fi * 16 + r0;
      float4 bv = *(const float4*)(bias + oo);
#pragma unroll
      for (int fj = 0; fj < 4; ++fj) {
        int mm = mb + fj * 16 + cm;
        int bb = mm >> 6, pix = mm & 63;
        size_t prow = (size_t)bb * 100 + 11 + (pix >> 3) * 10 + (pix & 7);
        unsigned short pk[4];
        pk[0] = f2bf(fmaxf(acc[fi][fj][0] + bv.x, 0.f));
        pk[1] = f2bf(fmaxf(acc[fi][fj][1] + bv.y, 0.f));
        pk[2] = f2bf(fmaxf(acc[fi][fj][2] + bv.z, 0.f));
        pk[3] = f2bf(fmaxf(acc[fi][fj][3] + bv.w, 0.f));
        *(ushort4*)(outp + prow * Cout + oo) = *(const ushort4*)pk;
      }
    }
  } else {
    float* out = (float*)outv + (size_t)blockIdx.z * zstride;
#pragma unroll
    for (int fi = 0; fi < 4; ++fi) {
#pragma unroll
      for (int fj = 0; fj < 4; ++fj) {
        int mm = mb + fj * 16 + cm;
        int bb = mm >> 6, pix = mm & 63;
#pragma unroll
        for (int r = 0; r < 4; ++r) {
          int oo = ob + fi * 16 + r0 + r;
          float v = acc[fi][fj][r];
          if (EPI == 0) v += bias[oo];
          out[((size_t)bb * Cout + oo) * 64 + pix] = v;
        }
      }
    }
  }
}

// ---------- sum proj partials for the q slice only, + bias, pre-scaled by 1/64 ----------
__global__ __launch_bounds__(256) void k_sum2q(const float* __restrict__ a,
                                               const float* __restrict__ b,
                                               const float* __restrict__ bias,
                                               float* __restrict__ q) {
  int e = (blockIdx.x * 256 + threadIdx.x) * 4;   // flat into 64x512x64
  int bb = e >> 15, rem = e & 32767;
  int ch = rem >> 6;
  size_t src = ((size_t)(bb * 1536 + 512 + ch) << 6) + (rem & 63);
  float4 va = *(const float4*)(a + src);
  float4 vb = *(const float4*)(b + src);
  float bs = bias[512 + ch];
  *(float4*)(q + e) = make_float4((va.x + vb.x + bs) * 0.015625f,
                                  (va.y + vb.y + bs) * 0.015625f,
                                  (va.z + vb.z + bs) * 0.015625f,
                                  (va.w + vb.w + bs) * 0.015625f);
}

// ---------- attention K-lite: logit = q.(ck+pw) all m; rk write only m==31 ----------
__global__ __launch_bounds__(256) void k_attnK(
    const float* __restrict__ qbuf, const float* __restrict__ kqvA,
    const float* __restrict__ kqvB, const float* __restrict__ projb,
    const float* __restrict__ ck, const float* __restrict__ pw,
    const float* __restrict__ pb, float* __restrict__ rk,
    float* __restrict__ logits) {
  int idx = blockIdx.x;
  int h = idx & 7, m = (idx >> 3) & 31, b = idx >> 8;
  int t = threadIdx.x, lane = t & 63, wid = t >> 6;
  int i0 = t << 4;
  int hd = i0 >> 6, pix = i0 & 63;

  const float* qs = qbuf + ((size_t)(b * 512 + h * 64 + hd) << 6) + pix;
  const float* pws = pw + ((size_t)m << 15) + (h << 12) + i0;

  float part = 0.f;
  if (m < 31) {
    const float* src = ck + (((size_t)(b * 32 + m + 1) * 8 + h) << 12) + i0;
#pragma unroll
    for (int j = 0; j < 4; ++j) {
      float4 a = *(const float4*)(src + j * 4);
      float4 p = *(const float4*)(pws + j * 4);
      float4 q = *(const float4*)(qs + j * 4);
      part += q.x * (a.x + p.x) + q.y * (a.y + p.y) + q.z * (a.z + p.z) + q.w * (a.w + p.w);
    }
  } else {
    size_t koff = ((size_t)(b * 1536 + h * 64 + hd) << 6) + pix;
    float bk = projb[h * 64 + hd];
    float* dst = rk + (((size_t)(b * 32 + 31) * 8 + h) << 12) + i0;
#pragma unroll
    for (int j = 0; j < 4; ++j) {
      float4 ka = *(const float4*)(kqvA + koff + j * 4);
      float4 kb = *(const float4*)(kqvB + koff + j * 4);
      float4 p = *(const float4*)(pws + j * 4);
      float4 q = *(const float4*)(qs + j * 4);
      float4 kk;
      kk.x = ka.x + kb.x + bk + p.x; kk.y = ka.y + kb.y + bk + p.y;
      kk.z = ka.z + kb.z + bk + p.z; kk.w = ka.w + kb.w + bk + p.w;
      *(float4*)(dst + j * 4) = kk;
      part += q.x * kk.x + q.y * kk.y + q.z * kk.z + q.w * kk.w;
    }
  }
#pragma unroll
  for (int s = 32; s; s >>= 1) part += __shfl_xor(part, s);
  __shared__ float red[4];
  if (lane == 0) red[wid] = part;
  __syncthreads();
  if (t == 0)
    logits[((b << 3) + h) * 32 + m] = red[0] + red[1] + red[2] + red[3] + pb[m * 8 + h];
}

// ---------- attention V-lite: softmax + attn -> apad (LDS transpose); rv write only m==31 ----------
__global__ __launch_bounds__(256) void k_attnV(
    const float* __restrict__ kqvA, const float* __restrict__ kqvB,
    const float* __restrict__ projb, const int* __restrict__ mask,
    const float* __restrict__ cv, const float* __restrict__ logits,
    float* __restrict__ rv, unsigned short* __restrict__ apad) {
  int bh = blockIdx.x, b = bh >> 3, h = bh & 7;
  int ych = blockIdx.y;
  int t = threadIdx.x;
  int d = (ych << 10) + (t << 2);
  int hd = d >> 6, pix = d & 63;

  float lg[32];
#pragma unroll
  for (int j = 0; j < 8; ++j) {
    float4 v = *(const float4*)(logits + bh * 32 + j * 4);
    lg[j * 4 + 0] = v.x; lg[j * 4 + 1] = v.y; lg[j * 4 + 2] = v.z; lg[j * 4 + 3] = v.w;
  }
  float mx = -INFINITY;
#pragma unroll
  for (int m = 0; m < 32; ++m) {
    if (m == 31) lg[m] += 5.0f;
    else if (mask[bh * 32 + m] != 0) lg[m] = -INFINITY;
    mx = fmaxf(mx, lg[m]);
  }
  float sm = 0.f;
#pragma unroll
  for (int m = 0; m < 32; ++m) { lg[m] = __expf(lg[m] - mx); sm += lg[m]; }
  float rs = 1.f / sm;

  float4 acc = make_float4(0.f, 0.f, 0.f, 0.f);
  for (int m = 0; m < 31; ++m) {
    const float* src = cv + (((size_t)(b * 32 + m + 1) * 8 + h) << 12) + d;
    float4 v = *(const float4*)src;
    float wm = lg[m] * rs;
    acc.x += wm * v.x; acc.y += wm * v.y; acc.z += wm * v.z; acc.w += wm * v.w;
  }
  {
    size_t voff = ((size_t)(b * 1536 + 1024 + h * 64 + hd) << 6) + pix;
    float bv = projb[1024 + h * 64 + hd];
    float4 va = *(const float4*)(kqvA + voff);
    float4 vb = *(const float4*)(kqvB + voff);
    float4 v;
    v.x = va.x + vb.x + bv; v.y = va.y + vb.y + bv;
    v.z = va.z + vb.z + bv; v.w = va.w + vb.w + bv;
    *(float4*)(rv + (((size_t)(b * 32 + 31) * 8 + h) << 12) + d) = v;
    float wm = lg[31] * rs;
    acc.x += wm * v.x; acc.y += wm * v.y; acc.z += wm * v.z; acc.w += wm * v.w;
  }

  // transpose [16 hd][64 pix] in LDS, write bf16 NHWC-padded
  __shared__ float lt[16][65];
  int hr = hd & 15;
  lt[hr][pix + 0] = acc.x; lt[hr][pix + 1] = acc.y;
  lt[hr][pix + 2] = acc.z; lt[hr][pix + 3] = acc.w;
  __syncthreads();
  int pw_ = t >> 2, hq = (t & 3) << 2;
  unsigned short pk[4];
#pragma unroll
  for (int j = 0; j < 4; ++j) pk[j] = f2bf(lt[hq + j][pw_]);
  size_t prow = (size_t)b * 100 + 11 + (pw_ >> 3) * 10 + (pw_ & 7);
  *(ushort4*)(apad + prow * 512 + h * 64 + (ych << 4) + hq) = *(const ushort4*)pk;
}

// ---------- LN stage 1: x = p0..p3 + resid + bias[ch]; write x + per-segment stats ----------
__global__ __launch_bounds__(256) void k_lnstat(
    const float* __restrict__ p, const float* __restrict__ resid,
    const float* __restrict__ bias, float* __restrict__ xbuf,
    float2* __restrict__ stat) {
  int bb = blockIdx.x, seg = blockIdx.y, t = threadIdx.x;
  int lane = t & 63, wid = t >> 6;
  size_t base = (size_t)bb << 15;
  float s = 0.f, sq = 0.f;
#pragma unroll
  for (int j = 0; j < 4; ++j) {
    int i = (seg << 12) + t * 4 + j * 1024;
    float4 v0 = *(const float4*)(p + base + i);
    float4 v1 = *(const float4*)(p + 2097152 + base + i);
    float4 v2 = *(const float4*)(p + 4194304 + base + i);
    float4 v3 = *(const float4*)(p + 6291456 + base + i);
    float4 vr = *(const float4*)(resid + base + i);
    float bs = bias[i >> 6];
    float4 xx;
    xx.x = v0.x + v1.x + v2.x + v3.x + vr.x + bs;
    xx.y = v0.y + v1.y + v2.y + v3.y + vr.y + bs;
    xx.z = v0.z + v1.z + v2.z + v3.z + vr.z + bs;
    xx.w = v0.w + v1.w + v2.w + v3.w + vr.w + bs;
    *(float4*)(xbuf + base + i) = xx;
    s += xx.x + xx.y + xx.z + xx.w;
    sq += xx.x * xx.x + xx.y * xx.y + xx.z * xx.z + xx.w * xx.w;
  }
#pragma unroll
  for (int k = 32; k; k >>= 1) { s += __shfl_xor(s, k); sq += __shfl_xor(sq, k); }
  __shared__ float rsm[4], rqm[4];
  if (lane == 0) { rsm[wid] = s; rqm[wid] = sq; }
  __syncthreads();
  if (t == 0)
    stat[bb * 8 + seg] = make_float2(rsm[0] + rsm[1] + rsm[2] + rsm[3],
                                     rqm[0] + rqm[1] + rqm[2] + rqm[3]);
}

// ---------- LN stage 2 (plain): normalize -> out ----------
__global__ __launch_bounds__(256) void k_lnapply(
    const float* __restrict__ xbuf, const float2* __restrict__ stat,
    const float* __restrict__ w, const float* __restrict__ beta,
    float* __restrict__ out) {
  int bb = blockIdx.x, seg = blockIdx.y, t = threadIdx.x;
  size_t base = (size_t)bb << 15;
  float s = 0.f, sq = 0.f;
#pragma unroll
  for (int k = 0; k < 8; ++k) {
    float2 st = stat[bb * 8 + k];
    s += st.x; sq += st.y;
  }
  float mean = s * (1.f / 32768.f);
  float var = sq * (1.f / 32768.f) - mean * mean;
  float rinv = rsqrtf(var + 1e-5f);
#pragma unroll
  for (int j = 0; j < 4; ++j) {
    int i = (seg << 12) + t * 4 + j * 1024;
    float4 xx = *(const float4*)(xbuf + base + i);
    float4 vw = *(const float4*)(w + i);
    float4 vt = *(const float4*)(beta + i);
    float4 r;
    r.x = (xx.x - mean) * rinv * vw.x + vt.x;
    r.y = (xx.y - mean) * rinv * vw.y + vt.y;
    r.z = (xx.z - mean) * rinv * vw.z + vt.z;
    r.w = (xx.w - mean) * rinv * vw.w + vt.w;
    *(float4*)(out + base + i) = r;
  }
}

// ---------- LN stage 2 fused with pad-transpose: normalize -> ln1 fp32 + l1pad bf16 ----------
__global__ __launch_bounds__(256) void k_lnpad(
    const float* __restrict__ xbuf, const float2* __restrict__ stat,
    const float* __restrict__ w, const float* __restrict__ beta,
    float* __restrict__ ln1, unsigned short* __restrict__ lp) {
  int b = blockIdx.x >> 3, c0 = (blockIdx.x & 7) << 6;
  int t = threadIdx.x;
  float s = 0.f, sq = 0.f;
#pragma unroll
  for (int k = 0; k < 8; ++k) {
    float2 st = stat[b * 8 + k];
    s += st.x; sq += st.y;
  }
  float mean = s * (1.f / 32768.f);
  float var = sq * (1.f / 32768.f) - mean * mean;
  float rinv = rsqrtf(var + 1e-5f);

  __shared__ float l[64][65];
  int cr = t >> 2, p0 = (t & 3) << 4;
  size_t off = ((size_t)b * 512 + c0 + cr) * 64 + p0;
  size_t woff = ((size_t)(c0 + cr)) * 64 + p0;
#pragma unroll
  for (int j = 0; j < 4; ++j) {
    float4 xx = *(const float4*)(xbuf + off + j * 4);
    float4 vw = *(const float4*)(w + woff + j * 4);
    float4 vt = *(const float4*)(beta + woff + j * 4);
    float4 r;
    r.x = (xx.x - mean) * rinv * vw.x + vt.x;
    r.y = (xx.y - mean) * rinv * vw.y + vt.y;
    r.z = (xx.z - mean) * rinv * vw.z + vt.z;
    r.w = (xx.w - mean) * rinv * vw.w + vt.w;
    *(float4*)(ln1 + off + j * 4) = r;
    l[cr][p0 + j * 4 + 0] = r.x; l[cr][p0 + j * 4 + 1] = r.y;
    l[cr][p0 + j * 4 + 2] = r.z; l[cr][p0 + j * 4 + 3] = r.w;
  }
  __syncthreads();
  int pix = t >> 2, cc0 = (t & 3) << 4;
  size_t prow = (size_t)b * 100 + 11 + (pix >> 3) * 10 + (pix & 7);
  unsigned short pk[16];
#pragma unroll
  for (int j = 0; j < 16; ++j) pk[j] = f2bf(l[cc0 + j][pix]);
  *(uint4*)(lp + prow * 512 + c0 + cc0) = *(const uint4*)pk;
  *(uint4*)(lp + prow * 512 + c0 + cc0 + 8) = *(const uint4*)(pk + 8);
}

extern "C" void kernel_launch(void* const* d_in, const int* in_sizes, int n_in,
                              void* d_out, int out_size, void* d_ws, size_t ws_size,
                              hipStream_t stream) {
  const float* x     = (const float*)d_in[0];
  const int*   mask  = (const int*)d_in[1];
  const float* ck    = (const float*)d_in[2];
  const float* cv    = (const float*)d_in[3];
  const float* projw = (const float*)d_in[4];
  const float* projb = (const float*)d_in[5];
  const float* outw  = (const float*)d_in[6];
  const float* outb  = (const float*)d_in[7];
  const float* l1w   = (const float*)d_in[8];
  const float* l1b   = (const float*)d_in[9];
  const float* l2w   = (const float*)d_in[10];
  const float* l2b   = (const float*)d_in[11];
  const float* n1w   = (const float*)d_in[12];
  const float* n1b   = (const float*)d_in[13];
  const float* n2w   = (const float*)d_in[14];
  const float* n2b   = (const float*)d_in[15];
  const float* posw  = (const float*)d_in[16];
  const float* posb  = (const float*)d_in[17];

  char* ws = (char*)d_ws;
  unsigned short* wbP   = (unsigned short*)(ws);             // 1536x4608
  unsigned short* wbO   = (unsigned short*)(ws + 14155776);  // 512x4608
  unsigned short* wbL1  = (unsigned short*)(ws + 18874368);  // 2048x4608
  unsigned short* wbL2  = (unsigned short*)(ws + 37748736);  // 512x18432
  unsigned short* xpadI = (unsigned short*)(ws + 56623104);  // 64x100x512
  unsigned short* apad  = (unsigned short*)(ws + 63176704);  // 64x100x512
  unsigned short* l1pad = (unsigned short*)(ws + 69730304);  // 64x100x512
  unsigned short* ffpad = (unsigned short*)(ws + 76283904);  // 64x100x2048
  float* kqvA   = (float*)(ws + 102498304);                  // proj partial z0
  float* kqvB   = (float*)(ws + 127664128);                  // proj partial z1
  float* qbuf   = (float*)(ws + 152829952);                  // 64x512x64 pre-scaled q
  float* logits = (float*)(ws + 177995776);                  // 512x32
  float* res    = (float*)(ws + 178061312);                  // 4 x 64x512x64 partials
  float* ln1    = (float*)(ws + 211615744);
  float* xbuf1  = (float*)(ws + 228392960);
  float* xbuf2  = (float*)(ws + 236781568);
  float2* stat1 = (float2*)(ws + 245170176);                 // 512 float2
  float2* stat2 = (float2*)(ws + 245174272);                 // ends ~245.2 MB

  float* out0 = (float*)d_out;
  float* rk = out0 + 2097152;
  float* rv = rk + 67108864;

  // merged border-zero + weight transforms + input pad
  k_prep<<<15872, 256, 0, stream>>>(projw, outw, l1w, l2w, x,
                                    wbP, wbO, wbL1, wbL2, xpadI, apad, l1pad, ffpad);

  // proj conv (split-K z=2) -> partials; q-slice sum (+bias, pre-scaled)
  k_gemm9<3><<<dim3(12, 32, 2), 256, 0, stream>>>(wbP, 4608, xpadI, 512, 3, 36, nullptr, kqvA, 1536, 6291456,
                                                  nullptr, nullptr, nullptr);
  k_sum2q<<<2048, 256, 0, stream>>>(kqvA, kqvB, projb, qbuf);

  // attention lite passes (logits + softmax + attn out + slot-31 writes only)
  k_attnK<<<16384, 256, 0, stream>>>(qbuf, kqvA, kqvB, projb, ck, posw, posb, rk, logits);
  k_attnV<<<dim3(512, 4), 256, 0, stream>>>(kqvA, kqvB, projb, mask, cv, logits, rv, apad);

  // out conv (split-K z=4) -> 4 partials; LN1 stats; fused LN1-apply + pad
  k_gemm9<3><<<dim3(4, 32, 4), 256, 0, stream>>>(wbO, 4608, apad, 512, 3, 18, nullptr, res, 512, 2097152,
                                                 nullptr, nullptr, nullptr);
  k_lnstat<<<dim3(64, 8), 256, 0, stream>>>(res, x, outb, xbuf1, stat1);
  k_lnpad<<<512, 256, 0, stream>>>(xbuf1, stat1, n1w, n1b, ln1, l1pad);

  // lin1 conv (+bias+relu) -> ffpad, weaving rk-bulk (rk[0..30] = ck[1..31]+pw)
  k_gemm9<4><<<dim3(16, 32, 1), 256, 0, stream>>>(wbL1, 4608, l1pad, 512, 3, 72, l1b, ffpad, 2048, 0,
                                                  ck, posw, rk);

  // lin2 conv (split-K z=4, 288 K-tiles) -> 4 partials, weaving rv-bulk (rv[0..30] = cv[1..31])
  k_gemm9<3><<<dim3(4, 32, 4), 256, 0, stream>>>(wbL2, 18432, ffpad, 2048, 5, 72, nullptr, res, 512, 2097152,
                                                 cv, nullptr, rv);
  k_lnstat<<<dim3(64, 8), 256, 0, stream>>>(res, ln1, l2b, xbuf2, stat2);
  k_lnapply<<<dim3(64, 8), 256, 0, stream>>>(xbuf2, stat2, n2w, n2b, out0);
}

// Round 11
// 747.998 us; speedup vs baseline: 1.1526x; 1.1526x over previous
//
#include <hip/hip_runtime.h>
#include <hip/hip_bf16.h>
#include <stdint.h>

// T=1, B=64, C=E=512, H=W=8, NH=8, HD=64, TOT=4096, MEM=32, FF=2048
typedef __attribute__((ext_vector_type(8))) short bf16x8;
typedef __attribute__((ext_vector_type(4))) float f32x4;

static __device__ __forceinline__ unsigned short f2bf(float f) {
  union { float f; unsigned int u; } v; v.f = f;
  unsigned int u = v.u;
  return (unsigned short)((u + 0x7FFFu + ((u >> 16) & 1u)) >> 16);
}

static __device__ __forceinline__ void gld16(const void* g, void* l) {
  __builtin_amdgcn_global_load_lds(
      (const __attribute__((address_space(1))) unsigned int*)g,
      (__attribute__((address_space(3))) unsigned int*)l, 16, 0, 0);
}

// ---------- merged: border-zero of 4 padded buffers + 4x weight transform + input pad ----------
__global__ __launch_bounds__(256) void k_prep(
    const float* __restrict__ projw, const float* __restrict__ outw,
    const float* __restrict__ l1w, const float* __restrict__ l2w,
    const float* __restrict__ x,
    unsigned short* __restrict__ wbP, unsigned short* __restrict__ wbO,
    unsigned short* __restrict__ wbL1, unsigned short* __restrict__ wbL2,
    unsigned short* __restrict__ xp, unsigned short* __restrict__ apad,
    unsigned short* __restrict__ l1pad, unsigned short* __restrict__ ffpad) {
  int bid = blockIdx.x, t = threadIdx.x;
  if (bid < 9216) {
    int buf = bid / 2304, rem = bid - buf * 2304;
    int b = rem / 36, ridx = rem - b * 36;
    int row;
    if (ridx < 11) row = ridx;
    else if (ridx < 25) { int p = ridx - 11; row = 19 + (p >> 1) * 10 + (p & 1); }
    else row = 89 + (ridx - 25);
    unsigned short* ptr; int C;
    switch (buf) {
      case 0: ptr = xp;    C = 512;  break;
      case 1: ptr = apad;  C = 512;  break;
      case 2: ptr = l1pad; C = 512;  break;
      default: ptr = ffpad; C = 2048; break;
    }
    int n16 = C >> 3;
    if (t < n16) *(uint4*)(ptr + ((size_t)b * 100 + row) * C + t * 8) = make_uint4(0u, 0u, 0u, 0u);
    return;
  }
  __shared__ float l[4608];
  int id = bid - 9216;
  if (id < 6144) {
    const float* in; unsigned short* out; int o, C, c0;
    if (id < 1536)      { in = projw; out = wbP;  o = id;               C = 512;  c0 = 0; }
    else if (id < 2048) { in = outw;  out = wbO;  o = id - 1536;        C = 512;  c0 = 0; }
    else if (id < 4096) { in = l1w;   out = wbL1; o = id - 2048;        C = 512;  c0 = 0; }
    else                { in = l2w;   out = wbL2; o = (id - 4096) >> 2; C = 2048; c0 = ((id - 4096) & 3) << 9; }
    const float* src = in + ((size_t)o * C + c0) * 9;
    for (int j = t; j < 4608; j += 256) l[j] = src[j];
    __syncthreads();
    unsigned short* dst = out + (size_t)o * 9 * C;
#pragma unroll
    for (int j = 0; j < 18; ++j) {
      int f = t * 18 + j;
      int tap = f >> 9, c = f & 511;
      dst[(size_t)tap * C + c0 + c] = f2bf(l[c * 9 + tap]);
    }
  } else {
    int idx = id - 6144;
    int b = idx >> 3, c0 = (idx & 7) << 6;
    float (*lt)[65] = (float(*)[65])l;
    int cr = t >> 2, p0 = (t & 3) << 4;
    const float* src = x + ((size_t)b * 512 + c0 + cr) * 64 + p0;
#pragma unroll
    for (int j = 0; j < 4; ++j) {
      float4 v = *(const float4*)(src + j * 4);
      lt[cr][p0 + j * 4 + 0] = v.x; lt[cr][p0 + j * 4 + 1] = v.y;
      lt[cr][p0 + j * 4 + 2] = v.z; lt[cr][p0 + j * 4 + 3] = v.w;
    }
    __syncthreads();
    int pix = t >> 2, cc0 = (t & 3) << 4;
    size_t prow = (size_t)b * 100 + 11 + (pix >> 3) * 10 + (pix & 7);
    unsigned short pk[16];
#pragma unroll
    for (int j = 0; j < 16; ++j) pk[j] = f2bf(lt[cc0 + j][pix]);
    *(uint4*)(xp + prow * 512 + c0 + cc0) = *(const uint4*)pk;
    *(uint4*)(xp + prow * 512 + c0 + cc0 + 8) = *(const uint4*)(pk + 8);
  }
}

// ---------- tap-shifted conv GEMM, double-buffered, 1 barrier/K-step ----------
// EPI: 0 = +bias fp32 NCHW; 3 = raw partial fp32 NCHW; 4 = +bias+relu bf16 NHWC-padded
template <int EPI>
__global__ __launch_bounds__(256, 2) void k_gemm9(
    const unsigned short* __restrict__ Wt, int ldK,
    const unsigned short* __restrict__ Xp, int C, int tlog,
    int kiter, const float* __restrict__ bias,
    void* __restrict__ outv, int Cout, size_t zstride) {
  __shared__ unsigned short lds[2][2][8192];
  int t = threadIdx.x, lane = t & 63, wid = t >> 6;

  int gx = gridDim.x;
  int f = blockIdx.x + blockIdx.y * gx;
  int cpx = (gx * gridDim.y) >> 3;
  int fs = (f & 7) * cpx + (f >> 3);
  int bx = fs % gx, by = fs / gx;

  int O0 = bx << 7, M0 = by << 7;
  int kbase = blockIdx.z * kiter;
  int srow = lane >> 3, skg = (lane & 7) << 3;

  int wrow[4], pbv[4];
#pragma unroll
  for (int i = 0; i < 4; ++i) {
    int rl = wid * 8 + i * 32 + srow;
    wrow[i] = O0 + rl;
    int m = M0 + rl, b = m >> 6, pix = m & 63;
    pbv[i] = b * 100 + (pix >> 3) * 10 + (pix & 7);
  }

  f32x4 acc[4][4];
#pragma unroll
  for (int i = 0; i < 4; ++i)
#pragma unroll
    for (int j = 0; j < 4; ++j) acc[i][j] = (f32x4){0.f, 0.f, 0.f, 0.f};

  auto stage = [&](int buf, int kt) {
    int gk = kbase + kt;
    int tap = gk >> tlog;
    int c0 = (gk - (tap << tlog)) << 6;
    int toff = tap + 7 * ((tap * 11) >> 5);  // ky*10+kx
#pragma unroll
    for (int i = 0; i < 4; ++i) {
      gld16(Wt + (size_t)wrow[i] * ldK + (gk << 6) + skg,
            &lds[buf][0][(wid * 8 + i * 32) * 64]);
      gld16(Xp + (size_t)(pbv[i] + toff) * C + c0 + skg,
            &lds[buf][1][(wid * 8 + i * 32) * 64]);
    }
  };

  int wr = wid >> 1, wc = wid & 1;
  int frow = lane & 15, fkb = (lane >> 4) << 3;

  auto compute = [&](int buf) {
    const unsigned short* Wl = &lds[buf][0][0];
    const unsigned short* Xl = &lds[buf][1][0];
#pragma unroll
    for (int kk = 0; kk < 2; ++kk) {
      bf16x8 af[4], bfv[4];
#pragma unroll
      for (int ff = 0; ff < 4; ++ff) {
        af[ff]  = *(const bf16x8*)(Wl + ((wr * 64 + ff * 16 + frow) << 6) + kk * 32 + fkb);
        bfv[ff] = *(const bf16x8*)(Xl + ((wc * 64 + ff * 16 + frow) << 6) + kk * 32 + fkb);
      }
#pragma unroll
      for (int fi = 0; fi < 4; ++fi)
#pragma unroll
        for (int fj = 0; fj < 4; ++fj)
          acc[fi][fj] = __builtin_amdgcn_mfma_f32_16x16x32_bf16(af[fi], bfv[fj], acc[fi][fj], 0, 0, 0);
    }
  };

  stage(0, 0);
  __syncthreads();
  for (int kt = 0; kt < kiter; ++kt) {
    int cur = kt & 1;
    if (kt + 1 < kiter) stage(cur ^ 1, kt + 1);
    compute(cur);
    __syncthreads();
  }

  int ob = O0 + wr * 64, mb = M0 + wc * 64;
  int r0 = (lane >> 4) << 2, cm = lane & 15;
  if (EPI == 4) {
    unsigned short* outp = (unsigned short*)outv;
#pragma unroll
    for (int fi = 0; fi < 4; ++fi) {
      int oo = ob + fi * 16 + r0;
      float4 bv = *(const float4*)(bias + oo);
#pragma unroll
      for (int fj = 0; fj < 4; ++fj) {
        int mm = mb + fj * 16 + cm;
        int bb = mm >> 6, pix = mm & 63;
        size_t prow = (size_t)bb * 100 + 11 + (pix >> 3) * 10 + (pix & 7);
        unsigned short pk[4];
        pk[0] = f2bf(fmaxf(acc[fi][fj][0] + bv.x, 0.f));
        pk[1] = f2bf(fmaxf(acc[fi][fj][1] + bv.y, 0.f));
        pk[2] = f2bf(fmaxf(acc[fi][fj][2] + bv.z, 0.f));
        pk[3] = f2bf(fmaxf(acc[fi][fj][3] + bv.w, 0.f));
        *(ushort4*)(outp + prow * Cout + oo) = *(const ushort4*)pk;
      }
    }
  } else {
    float* out = (float*)outv + (size_t)blockIdx.z * zstride;
#pragma unroll
    for (int fi = 0; fi < 4; ++fi) {
#pragma unroll
      for (int fj = 0; fj < 4; ++fj) {
        int mm = mb + fj * 16 + cm;
        int bb = mm >> 6, pix = mm & 63;
#pragma unroll
        for (int r = 0; r < 4; ++r) {
          int oo = ob + fi * 16 + r0 + r;
          float v = acc[fi][fj][r];
          if (EPI == 0) v += bias[oo];
          out[((size_t)bb * Cout + oo) * 64 + pix] = v;
        }
      }
    }
  }
}

// ---------- sum 4 proj partials for the q slice only, + bias, pre-scaled by 1/64 ----------
__global__ __launch_bounds__(256) void k_sum4q(const float* __restrict__ p,
                                               const float* __restrict__ bias,
                                               float* __restrict__ q) {
  int e = (blockIdx.x * 256 + threadIdx.x) * 4;   // flat into 64x512x64
  int bb = e >> 15, rem = e & 32767;
  int ch = rem >> 6;
  size_t src = ((size_t)(bb * 1536 + 512 + ch) << 6) + (rem & 63);
  float4 v0 = *(const float4*)(p + src);
  float4 v1 = *(const float4*)(p + 6291456 + src);
  float4 v2 = *(const float4*)(p + 12582912 + src);
  float4 v3 = *(const float4*)(p + 18874368 + src);
  float bs = bias[512 + ch];
  *(float4*)(q + e) = make_float4((v0.x + v1.x + v2.x + v3.x + bs) * 0.015625f,
                                  (v0.y + v1.y + v2.y + v3.y + bs) * 0.015625f,
                                  (v0.z + v1.z + v2.z + v3.z + bs) * 0.015625f,
                                  (v0.w + v1.w + v2.w + v3.w + bs) * 0.015625f);
}

// ---------- attention K-pass: rk = ck(+shift)+pw, logit = q.k (q pre-scaled) ----------
__global__ __launch_bounds__(256) void k_attnK(
    const float* __restrict__ qbuf, const float* __restrict__ kqv4,
    const float* __restrict__ projb, const float* __restrict__ ck,
    const float* __restrict__ pw, const float* __restrict__ pb,
    float* __restrict__ rk, float* __restrict__ logits) {
  int idx = blockIdx.x;
  int h = idx & 7, m = (idx >> 3) & 31, b = idx >> 8;
  int t = threadIdx.x, lane = t & 63, wid = t >> 6;
  int i0 = t << 4;
  int hd = i0 >> 6, pix = i0 & 63;

  const float* qs = qbuf + ((size_t)(b * 512 + h * 64 + hd) << 6) + pix;
  const float* pws = pw + ((size_t)m << 15) + (h << 12) + i0;
  float* dst = rk + (((size_t)(b * 32 + m) * 8 + h) << 12) + i0;

  float part = 0.f;
  if (m < 31) {
    const float* src = ck + (((size_t)(b * 32 + m + 1) * 8 + h) << 12) + i0;
#pragma unroll
    for (int j = 0; j < 4; ++j) {
      float4 a = *(const float4*)(src + j * 4);
      float4 p = *(const float4*)(pws + j * 4);
      float4 q = *(const float4*)(qs + j * 4);
      float4 kk;
      kk.x = a.x + p.x; kk.y = a.y + p.y; kk.z = a.z + p.z; kk.w = a.w + p.w;
      *(float4*)(dst + j * 4) = kk;
      part += q.x * kk.x + q.y * kk.y + q.z * kk.z + q.w * kk.w;
    }
  } else {
    size_t koff = ((size_t)(b * 1536 + h * 64 + hd) << 6) + pix;
    float bk = projb[h * 64 + hd];
#pragma unroll
    for (int j = 0; j < 4; ++j) {
      float4 k0 = *(const float4*)(kqv4 + koff + j * 4);
      float4 k1 = *(const float4*)(kqv4 + 6291456 + koff + j * 4);
      float4 k2 = *(const float4*)(kqv4 + 12582912 + koff + j * 4);
      float4 k3 = *(const float4*)(kqv4 + 18874368 + koff + j * 4);
      float4 p = *(const float4*)(pws + j * 4);
      float4 q = *(const float4*)(qs + j * 4);
      float4 kk;
      kk.x = k0.x + k1.x + k2.x + k3.x + bk + p.x;
      kk.y = k0.y + k1.y + k2.y + k3.y + bk + p.y;
      kk.z = k0.z + k1.z + k2.z + k3.z + bk + p.z;
      kk.w = k0.w + k1.w + k2.w + k3.w + bk + p.w;
      *(float4*)(dst + j * 4) = kk;
      part += q.x * kk.x + q.y * kk.y + q.z * kk.z + q.w * kk.w;
    }
  }
#pragma unroll
  for (int s = 32; s; s >>= 1) part += __shfl_xor(part, s);
  __shared__ float red[4];
  if (lane == 0) red[wid] = part;
  __syncthreads();
  if (t == 0)
    logits[((b << 3) + h) * 32 + m] = red[0] + red[1] + red[2] + red[3] + pb[m * 8 + h];
}

// ---------- attention V-pass: softmax + rv (all m) + attn -> apad (LDS transpose) ----------
__global__ __launch_bounds__(256) void k_attnV(
    const float* __restrict__ kqv4, const float* __restrict__ projb,
    const int* __restrict__ mask, const float* __restrict__ cv,
    const float* __restrict__ logits, float* __restrict__ rv,
    unsigned short* __restrict__ apad) {
  int bh = blockIdx.x, b = bh >> 3, h = bh & 7;
  int ych = blockIdx.y;
  int t = threadIdx.x;
  int d = (ych << 10) + (t << 2);
  int hd = d >> 6, pix = d & 63;

  float lg[32];
#pragma unroll
  for (int j = 0; j < 8; ++j) {
    float4 v = *(const float4*)(logits + bh * 32 + j * 4);
    lg[j * 4 + 0] = v.x; lg[j * 4 + 1] = v.y; lg[j * 4 + 2] = v.z; lg[j * 4 + 3] = v.w;
  }
  float mx = -INFINITY;
#pragma unroll
  for (int m = 0; m < 32; ++m) {
    if (m == 31) lg[m] += 5.0f;
    else if (mask[bh * 32 + m] != 0) lg[m] = -INFINITY;
    mx = fmaxf(mx, lg[m]);
  }
  float sm = 0.f;
#pragma unroll
  for (int m = 0; m < 32; ++m) { lg[m] = __expf(lg[m] - mx); sm += lg[m]; }
  float rs = 1.f / sm;

  float4 acc = make_float4(0.f, 0.f, 0.f, 0.f);
  for (int m = 0; m < 31; ++m) {
    const float* src = cv + (((size_t)(b * 32 + m + 1) * 8 + h) << 12) + d;
    float4 v = *(const float4*)src;
    *(float4*)(rv + (((size_t)(b * 32 + m) * 8 + h) << 12) + d) = v;
    float wm = lg[m] * rs;
    acc.x += wm * v.x; acc.y += wm * v.y; acc.z += wm * v.z; acc.w += wm * v.w;
  }
  {
    size_t voff = ((size_t)(b * 1536 + 1024 + h * 64 + hd) << 6) + pix;
    float bv = projb[1024 + h * 64 + hd];
    float4 v0 = *(const float4*)(kqv4 + voff);
    float4 v1 = *(const float4*)(kqv4 + 6291456 + voff);
    float4 v2 = *(const float4*)(kqv4 + 12582912 + voff);
    float4 v3 = *(const float4*)(kqv4 + 18874368 + voff);
    float4 v;
    v.x = v0.x + v1.x + v2.x + v3.x + bv;
    v.y = v0.y + v1.y + v2.y + v3.y + bv;
    v.z = v0.z + v1.z + v2.z + v3.z + bv;
    v.w = v0.w + v1.w + v2.w + v3.w + bv;
    *(float4*)(rv + (((size_t)(b * 32 + 31) * 8 + h) << 12) + d) = v;
    float wm = lg[31] * rs;
    acc.x += wm * v.x; acc.y += wm * v.y; acc.z += wm * v.z; acc.w += wm * v.w;
  }

  // transpose [16 hd][64 pix] in LDS, write bf16 NHWC-padded directly
  __shared__ float lt[16][65];
  int hr = hd & 15;
  lt[hr][pix + 0] = acc.x; lt[hr][pix + 1] = acc.y;
  lt[hr][pix + 2] = acc.z; lt[hr][pix + 3] = acc.w;
  __syncthreads();
  int pw_ = t >> 2, hq = (t & 3) << 2;
  unsigned short pk[4];
#pragma unroll
  for (int j = 0; j < 4; ++j) pk[j] = f2bf(lt[hq + j][pw_]);
  size_t prow = (size_t)b * 100 + 11 + (pw_ >> 3) * 10 + (pw_ & 7);
  *(ushort4*)(apad + prow * 512 + h * 64 + (ych << 4) + hq) = *(const ushort4*)pk;
}

// ---------- LN stage 1: x = p0..p3 + resid + bias[ch]; write x + per-segment stats ----------
__global__ __launch_bounds__(256) void k_lnstat(
    const float* __restrict__ p, const float* __restrict__ resid,
    const float* __restrict__ bias, float* __restrict__ xbuf,
    float2* __restrict__ stat) {
  int bb = blockIdx.x, seg = blockIdx.y, t = threadIdx.x;
  int lane = t & 63, wid = t >> 6;
  size_t base = (size_t)bb << 15;
  float s = 0.f, sq = 0.f;
#pragma unroll
  for (int j = 0; j < 4; ++j) {
    int i = (seg << 12) + t * 4 + j * 1024;
    float4 v0 = *(const float4*)(p + base + i);
    float4 v1 = *(const float4*)(p + 2097152 + base + i);
    float4 v2 = *(const float4*)(p + 4194304 + base + i);
    float4 v3 = *(const float4*)(p + 6291456 + base + i);
    float4 vr = *(const float4*)(resid + base + i);
    float bs = bias[i >> 6];
    float4 xx;
    xx.x = v0.x + v1.x + v2.x + v3.x + vr.x + bs;
    xx.y = v0.y + v1.y + v2.y + v3.y + vr.y + bs;
    xx.z = v0.z + v1.z + v2.z + v3.z + vr.z + bs;
    xx.w = v0.w + v1.w + v2.w + v3.w + vr.w + bs;
    *(float4*)(xbuf + base + i) = xx;
    s += xx.x + xx.y + xx.z + xx.w;
    sq += xx.x * xx.x + xx.y * xx.y + xx.z * xx.z + xx.w * xx.w;
  }
#pragma unroll
  for (int k = 32; k; k >>= 1) { s += __shfl_xor(s, k); sq += __shfl_xor(sq, k); }
  __shared__ float rsm[4], rqm[4];
  if (lane == 0) { rsm[wid] = s; rqm[wid] = sq; }
  __syncthreads();
  if (t == 0)
    stat[bb * 8 + seg] = make_float2(rsm[0] + rsm[1] + rsm[2] + rsm[3],
                                     rqm[0] + rqm[1] + rqm[2] + rqm[3]);
}

// ---------- LN stage 2 (plain): normalize -> out ----------
__global__ __launch_bounds__(256) void k_lnapply(
    const float* __restrict__ xbuf, const float2* __restrict__ stat,
    const float* __restrict__ w, const float* __restrict__ beta,
    float* __restrict__ out) {
  int bb = blockIdx.x, seg = blockIdx.y, t = threadIdx.x;
  size_t base = (size_t)bb << 15;
  float s = 0.f, sq = 0.f;
#pragma unroll
  for (int k = 0; k < 8; ++k) {
    float2 st = stat[bb * 8 + k];
    s += st.x; sq += st.y;
  }
  float mean = s * (1.f / 32768.f);
  float var = sq * (1.f / 32768.f) - mean * mean;
  float rinv = rsqrtf(var + 1e-5f);
#pragma unroll
  for (int j = 0; j < 4; ++j) {
    int i = (seg << 12) + t * 4 + j * 1024;
    float4 xx = *(const float4*)(xbuf + base + i);
    float4 vw = *(const float4*)(w + i);
    float4 vt = *(const float4*)(beta + i);
    float4 r;
    r.x = (xx.x - mean) * rinv * vw.x + vt.x;
    r.y = (xx.y - mean) * rinv * vw.y + vt.y;
    r.z = (xx.z - mean) * rinv * vw.z + vt.z;
    r.w = (xx.w - mean) * rinv * vw.w + vt.w;
    *(float4*)(out + base + i) = r;
  }
}

// ---------- LN stage 2 fused with pad-transpose: normalize -> ln1 fp32 + l1pad bf16 ----------
__global__ __launch_bounds__(256) void k_lnpad(
    const float* __restrict__ xbuf, const float2* __restrict__ stat,
    const float* __restrict__ w, const float* __restrict__ beta,
    float* __restrict__ ln1, unsigned short* __restrict__ lp) {
  int b = blockIdx.x >> 3, c0 = (blockIdx.x & 7) << 6;
  int t = threadIdx.x;
  float s = 0.f, sq = 0.f;
#pragma unroll
  for (int k = 0; k < 8; ++k) {
    float2 st = stat[b * 8 + k];
    s += st.x; sq += st.y;
  }
  float mean = s * (1.f / 32768.f);
  float var = sq * (1.f / 32768.f) - mean * mean;
  float rinv = rsqrtf(var + 1e-5f);

  __shared__ float l[64][65];
  int cr = t >> 2, p0 = (t & 3) << 4;
  size_t off = ((size_t)b * 512 + c0 + cr) * 64 + p0;
  size_t woff = ((size_t)(c0 + cr)) * 64 + p0;
#pragma unroll
  for (int j = 0; j < 4; ++j) {
    float4 xx = *(const float4*)(xbuf + off + j * 4);
    float4 vw = *(const float4*)(w + woff + j * 4);
    float4 vt = *(const float4*)(beta + woff + j * 4);
    float4 r;
    r.x = (xx.x - mean) * rinv * vw.x + vt.x;
    r.y = (xx.y - mean) * rinv * vw.y + vt.y;
    r.z = (xx.z - mean) * rinv * vw.z + vt.z;
    r.w = (xx.w - mean) * rinv * vw.w + vt.w;
    *(float4*)(ln1 + off + j * 4) = r;
    l[cr][p0 + j * 4 + 0] = r.x; l[cr][p0 + j * 4 + 1] = r.y;
    l[cr][p0 + j * 4 + 2] = r.z; l[cr][p0 + j * 4 + 3] = r.w;
  }
  __syncthreads();
  int pix = t >> 2, cc0 = (t & 3) << 4;
  size_t prow = (size_t)b * 100 + 11 + (pix >> 3) * 10 + (pix & 7);
  unsigned short pk[16];
#pragma unroll
  for (int j = 0; j < 16; ++j) pk[j] = f2bf(l[cc0 + j][pix]);
  *(uint4*)(lp + prow * 512 + c0 + cc0) = *(const uint4*)pk;
  *(uint4*)(lp + prow * 512 + c0 + cc0 + 8) = *(const uint4*)(pk + 8);
}

extern "C" void kernel_launch(void* const* d_in, const int* in_sizes, int n_in,
                              void* d_out, int out_size, void* d_ws, size_t ws_size,
                              hipStream_t stream) {
  const float* x     = (const float*)d_in[0];
  const int*   mask  = (const int*)d_in[1];
  const float* ck    = (const float*)d_in[2];
  const float* cv    = (const float*)d_in[3];
  const float* projw = (const float*)d_in[4];
  const float* projb = (const float*)d_in[5];
  const float* outw  = (const float*)d_in[6];
  const float* outb  = (const float*)d_in[7];
  const float* l1w   = (const float*)d_in[8];
  const float* l1b   = (const float*)d_in[9];
  const float* l2w   = (const float*)d_in[10];
  const float* l2b   = (const float*)d_in[11];
  const float* n1w   = (const float*)d_in[12];
  const float* n1b   = (const float*)d_in[13];
  const float* n2w   = (const float*)d_in[14];
  const float* n2b   = (const float*)d_in[15];
  const float* posw  = (const float*)d_in[16];
  const float* posb  = (const float*)d_in[17];

  char* ws = (char*)d_ws;
  unsigned short* wbP   = (unsigned short*)(ws);             // 1536x4608
  unsigned short* wbO   = (unsigned short*)(ws + 14155776);  // 512x4608
  unsigned short* wbL1  = (unsigned short*)(ws + 18874368);  // 2048x4608
  unsigned short* wbL2  = (unsigned short*)(ws + 37748736);  // 512x18432
  unsigned short* xpadI = (unsigned short*)(ws + 56623104);  // 64x100x512
  unsigned short* apad  = (unsigned short*)(ws + 63176704);  // 64x100x512
  unsigned short* l1pad = (unsigned short*)(ws + 69730304);  // 64x100x512
  unsigned short* ffpad = (unsigned short*)(ws + 76283904);  // 64x100x2048
  float* kqv4   = (float*)(ws + 102498304);                  // 4 x 64x1536x64 proj partials
  float* qbuf   = (float*)(ws + 203161600);                  // 64x512x64 pre-scaled q
  float* logits = (float*)(ws + 211550208);                  // 512x32
  float* res    = (float*)(ws + 211615744);                  // 4 x 64x512x64 partials
  float* ln1    = (float*)(ws + 245170176);
  float* xbuf1  = (float*)(ws + 253558784);
  float* xbuf2  = (float*)(ws + 261947392);
  float2* stat1 = (float2*)(ws + 270336000);                 // 512 float2
  float2* stat2 = (float2*)(ws + 270340096);                 // ends ~270.3 MB

  float* out0 = (float*)d_out;
  float* rk = out0 + 2097152;
  float* rv = rk + 67108864;

  // merged border-zero + weight transforms + input pad
  k_prep<<<15872, 256, 0, stream>>>(projw, outw, l1w, l2w, x,
                                    wbP, wbO, wbL1, wbL2, xpadI, apad, l1pad, ffpad);

  // proj conv (split-K z=4: 1536 blocks = 3 exact co-residency rounds) -> 4 partials
  k_gemm9<3><<<dim3(12, 32, 4), 256, 0, stream>>>(wbP, 4608, xpadI, 512, 3, 18, nullptr, kqv4, 1536, 6291456);
  k_sum4q<<<2048, 256, 0, stream>>>(kqv4, projb, qbuf);

  // attention (full rk/rv writes; q pre-summed; k/v partial-sum only at m==31)
  k_attnK<<<16384, 256, 0, stream>>>(qbuf, kqv4, projb, ck, posw, posb, rk, logits);
  k_attnV<<<dim3(512, 4), 256, 0, stream>>>(kqv4, projb, mask, cv, logits, rv, apad);

  // out conv (split-K z=4) -> 4 partials; LN1 stats; fused LN1-apply + pad
  k_gemm9<3><<<dim3(4, 32, 4), 256, 0, stream>>>(wbO, 4608, apad, 512, 3, 18, nullptr, res, 512, 2097152);
  k_lnstat<<<dim3(64, 8), 256, 0, stream>>>(res, x, outb, xbuf1, stat1);
  k_lnpad<<<512, 256, 0, stream>>>(xbuf1, stat1, n1w, n1b, ln1, l1pad);

  // lin1 conv (+bias+relu) -> ffpad
  k_gemm9<4><<<dim3(16, 32, 1), 256, 0, stream>>>(wbL1, 4608, l1pad, 512, 3, 72, l1b, ffpad, 2048, 0);

  // lin2 conv (split-K z=4, 288 K-tiles) -> 4 partials; LN2 (+bias +ln1 residual) -> out
  k_gemm9<3><<<dim3(4, 32, 4), 256, 0, stream>>>(wbL2, 18432, ffpad, 2048, 5, 72, nullptr, res, 512, 2097152);
  k_lnstat<<<dim3(64, 8), 256, 0, stream>>>(res, ln1, l2b, xbuf2, stat2);
  k_lnapply<<<dim3(64, 8), 256, 0, stream>>>(xbuf2, stat2, n2w, n2b, out0);
}

// Round 12
// 732.713 us; speedup vs baseline: 1.1766x; 1.0209x over previous
//
#include <hip/hip_runtime.h>
#include <hip/hip_bf16.h>
#include <stdint.h>

// T=1, B=64, C=E=512, H=W=8, NH=8, HD=64, TOT=4096, MEM=32, FF=2048
typedef __attribute__((ext_vector_type(8))) short bf16x8;
typedef __attribute__((ext_vector_type(4))) float f32x4;

static __device__ __forceinline__ unsigned short f2bf(float f) {
  union { float f; unsigned int u; } v; v.f = f;
  unsigned int u = v.u;
  return (unsigned short)((u + 0x7FFFu + ((u >> 16) & 1u)) >> 16);
}

static __device__ __forceinline__ void gld16(const void* g, void* l) {
  __builtin_amdgcn_global_load_lds(
      (const __attribute__((address_space(1))) unsigned int*)g,
      (__attribute__((address_space(3))) unsigned int*)l, 16, 0, 0);
}

// ---------- merged: border-zero of 4 padded buffers + 4x weight transform + input pad ----------
__global__ __launch_bounds__(256) void k_prep(
    const float* __restrict__ projw, const float* __restrict__ outw,
    const float* __restrict__ l1w, const float* __restrict__ l2w,
    const float* __restrict__ x,
    unsigned short* __restrict__ wbP, unsigned short* __restrict__ wbO,
    unsigned short* __restrict__ wbL1, unsigned short* __restrict__ wbL2,
    unsigned short* __restrict__ xp, unsigned short* __restrict__ apad,
    unsigned short* __restrict__ l1pad, unsigned short* __restrict__ ffpad) {
  int bid = blockIdx.x, t = threadIdx.x;
  if (bid < 9216) {
    int buf = bid / 2304, rem = bid - buf * 2304;
    int b = rem / 36, ridx = rem - b * 36;
    int row;
    if (ridx < 11) row = ridx;
    else if (ridx < 25) { int p = ridx - 11; row = 19 + (p >> 1) * 10 + (p & 1); }
    else row = 89 + (ridx - 25);
    unsigned short* ptr; int C;
    switch (buf) {
      case 0: ptr = xp;    C = 512;  break;
      case 1: ptr = apad;  C = 512;  break;
      case 2: ptr = l1pad; C = 512;  break;
      default: ptr = ffpad; C = 2048; break;
    }
    int n16 = C >> 3;
    if (t < n16) *(uint4*)(ptr + ((size_t)b * 100 + row) * C + t * 8) = make_uint4(0u, 0u, 0u, 0u);
    return;
  }
  __shared__ float l[4608];
  int id = bid - 9216;
  if (id < 6144) {
    const float* in; unsigned short* out; int o, C, c0;
    if (id < 1536)      { in = projw; out = wbP;  o = id;               C = 512;  c0 = 0; }
    else if (id < 2048) { in = outw;  out = wbO;  o = id - 1536;        C = 512;  c0 = 0; }
    else if (id < 4096) { in = l1w;   out = wbL1; o = id - 2048;        C = 512;  c0 = 0; }
    else                { in = l2w;   out = wbL2; o = (id - 4096) >> 2; C = 2048; c0 = ((id - 4096) & 3) << 9; }
    const float* src = in + ((size_t)o * C + c0) * 9;
    for (int j = t; j < 4608; j += 256) l[j] = src[j];
    __syncthreads();
    unsigned short* dst = out + (size_t)o * 9 * C;
#pragma unroll
    for (int j = 0; j < 18; ++j) {
      int f = t * 18 + j;
      int tap = f >> 9, c = f & 511;
      dst[(size_t)tap * C + c0 + c] = f2bf(l[c * 9 + tap]);
    }
  } else {
    int idx = id - 6144;
    int b = idx >> 3, c0 = (idx & 7) << 6;
    float (*lt)[65] = (float(*)[65])l;
    int cr = t >> 2, p0 = (t & 3) << 4;
    const float* src = x + ((size_t)b * 512 + c0 + cr) * 64 + p0;
#pragma unroll
    for (int j = 0; j < 4; ++j) {
      float4 v = *(const float4*)(src + j * 4);
      lt[cr][p0 + j * 4 + 0] = v.x; lt[cr][p0 + j * 4 + 1] = v.y;
      lt[cr][p0 + j * 4 + 2] = v.z; lt[cr][p0 + j * 4 + 3] = v.w;
    }
    __syncthreads();
    int pix = t >> 2, cc0 = (t & 3) << 4;
    size_t prow = (size_t)b * 100 + 11 + (pix >> 3) * 10 + (pix & 7);
    unsigned short pk[16];
#pragma unroll
    for (int j = 0; j < 16; ++j) pk[j] = f2bf(lt[cc0 + j][pix]);
    *(uint4*)(xp + prow * 512 + c0 + cc0) = *(const uint4*)pk;
    *(uint4*)(xp + prow * 512 + c0 + cc0 + 8) = *(const uint4*)(pk + 8);
  }
}

// ---------- NCHW fp32 -> padded NHWC bf16 (attnb -> apad) ----------
__global__ __launch_bounds__(256) void k_x2pad(const float* __restrict__ x,
                                               unsigned short* __restrict__ xp) {
  int b = blockIdx.x >> 3, c0 = (blockIdx.x & 7) << 6;
  int t = threadIdx.x;
  __shared__ float l[64][65];
  int cr = t >> 2, p0 = (t & 3) << 4;
  const float* src = x + ((size_t)b * 512 + c0 + cr) * 64 + p0;
#pragma unroll
  for (int j = 0; j < 4; ++j) {
    float4 v = *(const float4*)(src + j * 4);
    l[cr][p0 + j * 4 + 0] = v.x; l[cr][p0 + j * 4 + 1] = v.y;
    l[cr][p0 + j * 4 + 2] = v.z; l[cr][p0 + j * 4 + 3] = v.w;
  }
  __syncthreads();
  int pix = t >> 2, cc0 = (t & 3) << 4;
  size_t prow = (size_t)b * 100 + 11 + (pix >> 3) * 10 + (pix & 7);
  unsigned short pk[16];
#pragma unroll
  for (int j = 0; j < 16; ++j) pk[j] = f2bf(l[cc0 + j][pix]);
  *(uint4*)(xp + prow * 512 + c0 + cc0) = *(const uint4*)pk;
  *(uint4*)(xp + prow * 512 + c0 + cc0 + 8) = *(const uint4*)(pk + 8);
}

// ---------- tap-shifted conv GEMM, double-buffered, 1 barrier/K-step ----------
// EPI: 0 = +bias fp32 NCHW; 3 = raw partial fp32 NCHW; 4 = +bias+relu bf16 NHWC-padded
template <int EPI>
__global__ __launch_bounds__(256, 2) void k_gemm9(
    const unsigned short* __restrict__ Wt, int ldK,
    const unsigned short* __restrict__ Xp, int C, int tlog,
    int kiter, const float* __restrict__ bias,
    void* __restrict__ outv, int Cout, size_t zstride) {
  __shared__ unsigned short lds[2][2][8192];
  int t = threadIdx.x, lane = t & 63, wid = t >> 6;

  int gx = gridDim.x;
  int f = blockIdx.x + blockIdx.y * gx;
  int cpx = (gx * gridDim.y) >> 3;
  int fs = (f & 7) * cpx + (f >> 3);
  int bx = fs % gx, by = fs / gx;

  int O0 = bx << 7, M0 = by << 7;
  int kbase = blockIdx.z * kiter;
  int srow = lane >> 3, skg = (lane & 7) << 3;

  int wrow[4], pbv[4];
#pragma unroll
  for (int i = 0; i < 4; ++i) {
    int rl = wid * 8 + i * 32 + srow;
    wrow[i] = O0 + rl;
    int m = M0 + rl, b = m >> 6, pix = m & 63;
    pbv[i] = b * 100 + (pix >> 3) * 10 + (pix & 7);
  }

  f32x4 acc[4][4];
#pragma unroll
  for (int i = 0; i < 4; ++i)
#pragma unroll
    for (int j = 0; j < 4; ++j) acc[i][j] = (f32x4){0.f, 0.f, 0.f, 0.f};

  auto stage = [&](int buf, int kt) {
    int gk = kbase + kt;
    int tap = gk >> tlog;
    int c0 = (gk - (tap << tlog)) << 6;
    int toff = tap + 7 * ((tap * 11) >> 5);  // ky*10+kx
#pragma unroll
    for (int i = 0; i < 4; ++i) {
      gld16(Wt + (size_t)wrow[i] * ldK + (gk << 6) + skg,
            &lds[buf][0][(wid * 8 + i * 32) * 64]);
      gld16(Xp + (size_t)(pbv[i] + toff) * C + c0 + skg,
            &lds[buf][1][(wid * 8 + i * 32) * 64]);
    }
  };

  int wr = wid >> 1, wc = wid & 1;
  int frow = lane & 15, fkb = (lane >> 4) << 3;

  auto compute = [&](int buf) {
    const unsigned short* Wl = &lds[buf][0][0];
    const unsigned short* Xl = &lds[buf][1][0];
#pragma unroll
    for (int kk = 0; kk < 2; ++kk) {
      bf16x8 af[4], bfv[4];
#pragma unroll
      for (int ff = 0; ff < 4; ++ff) {
        af[ff]  = *(const bf16x8*)(Wl + ((wr * 64 + ff * 16 + frow) << 6) + kk * 32 + fkb);
        bfv[ff] = *(const bf16x8*)(Xl + ((wc * 64 + ff * 16 + frow) << 6) + kk * 32 + fkb);
      }
#pragma unroll
      for (int fi = 0; fi < 4; ++fi)
#pragma unroll
        for (int fj = 0; fj < 4; ++fj)
          acc[fi][fj] = __builtin_amdgcn_mfma_f32_16x16x32_bf16(af[fi], bfv[fj], acc[fi][fj], 0, 0, 0);
    }
  };

  stage(0, 0);
  __syncthreads();
  for (int kt = 0; kt < kiter; ++kt) {
    int cur = kt & 1;
    if (kt + 1 < kiter) stage(cur ^ 1, kt + 1);
    compute(cur);
    __syncthreads();
  }

  int ob = O0 + wr * 64, mb = M0 + wc * 64;
  int r0 = (lane >> 4) << 2, cm = lane & 15;
  if (EPI == 4) {
    unsigned short* outp = (unsigned short*)outv;
#pragma unroll
    for (int fi = 0; fi < 4; ++fi) {
      int oo = ob + fi * 16 + r0;
      float4 bv = *(const float4*)(bias + oo);
#pragma unroll
      for (int fj = 0; fj < 4; ++fj) {
        int mm = mb + fj * 16 + cm;
        int bb = mm >> 6, pix = mm & 63;
        size_t prow = (size_t)bb * 100 + 11 + (pix >> 3) * 10 + (pix & 7);
        unsigned short pk[4];
        pk[0] = f2bf(fmaxf(acc[fi][fj][0] + bv.x, 0.f));
        pk[1] = f2bf(fmaxf(acc[fi][fj][1] + bv.y, 0.f));
        pk[2] = f2bf(fmaxf(acc[fi][fj][2] + bv.z, 0.f));
        pk[3] = f2bf(fmaxf(acc[fi][fj][3] + bv.w, 0.f));
        *(ushort4*)(outp + prow * Cout + oo) = *(const ushort4*)pk;
      }
    }
  } else {
    float* out = (float*)outv + (size_t)blockIdx.z * zstride;
#pragma unroll
    for (int fi = 0; fi < 4; ++fi) {
#pragma unroll
      for (int fj = 0; fj < 4; ++fj) {
        int mm = mb + fj * 16 + cm;
        int bb = mm >> 6, pix = mm & 63;
#pragma unroll
        for (int r = 0; r < 4; ++r) {
          int oo = ob + fi * 16 + r0 + r;
          float v = acc[fi][fj][r];
          if (EPI == 0) v += bias[oo];
          out[((size_t)bb * Cout + oo) * 64 + pix] = v;
        }
      }
    }
  }
}

// ---------- sum proj partials for the q slice only, + bias, pre-scaled by 1/64 ----------
__global__ __launch_bounds__(256) void k_sum2q(const float* __restrict__ a,
                                               const float* __restrict__ b,
                                               const float* __restrict__ bias,
                                               float* __restrict__ q) {
  int e = (blockIdx.x * 256 + threadIdx.x) * 4;   // flat into 64x512x64
  int bb = e >> 15, rem = e & 32767;
  int ch = rem >> 6;
  size_t src = ((size_t)(bb * 1536 + 512 + ch) << 6) + (rem & 63);
  float4 va = *(const float4*)(a + src);
  float4 vb = *(const float4*)(b + src);
  float bs = bias[512 + ch];
  *(float4*)(q + e) = make_float4((va.x + vb.x + bs) * 0.015625f,
                                  (va.y + vb.y + bs) * 0.015625f,
                                  (va.z + vb.z + bs) * 0.015625f,
                                  (va.w + vb.w + bs) * 0.015625f);
}

// ---------- attention K-pass: rk = ck(+shift)+pw, logit = q.k (q pre-scaled) ----------
__global__ __launch_bounds__(256) void k_attnK(
    const float* __restrict__ qbuf, const float* __restrict__ kqvA,
    const float* __restrict__ kqvB, const float* __restrict__ projb,
    const float* __restrict__ ck, const float* __restrict__ pw,
    const float* __restrict__ pb, float* __restrict__ rk,
    float* __restrict__ logits) {
  int idx = blockIdx.x;
  int h = idx & 7, m = (idx >> 3) & 31, b = idx >> 8;
  int t = threadIdx.x, lane = t & 63, wid = t >> 6;
  int i0 = t << 4;
  int hd = i0 >> 6, pix = i0 & 63;

  const float* qs = qbuf + ((size_t)(b * 512 + h * 64 + hd) << 6) + pix;
  const float* pws = pw + ((size_t)m << 15) + (h << 12) + i0;
  float* dst = rk + (((size_t)(b * 32 + m) * 8 + h) << 12) + i0;

  float part = 0.f;
  if (m < 31) {
    const float* src = ck + (((size_t)(b * 32 + m + 1) * 8 + h) << 12) + i0;
#pragma unroll
    for (int j = 0; j < 4; ++j) {
      float4 a = *(const float4*)(src + j * 4);
      float4 p = *(const float4*)(pws + j * 4);
      float4 q = *(const float4*)(qs + j * 4);
      float4 kk;
      kk.x = a.x + p.x; kk.y = a.y + p.y; kk.z = a.z + p.z; kk.w = a.w + p.w;
      *(float4*)(dst + j * 4) = kk;
      part += q.x * kk.x + q.y * kk.y + q.z * kk.z + q.w * kk.w;
    }
  } else {
    size_t koff = ((size_t)(b * 1536 + h * 64 + hd) << 6) + pix;
    float bk = projb[h * 64 + hd];
#pragma unroll
    for (int j = 0; j < 4; ++j) {
      float4 ka = *(const float4*)(kqvA + koff + j * 4);
      float4 kb = *(const float4*)(kqvB + koff + j * 4);
      float4 p = *(const float4*)(pws + j * 4);
      float4 q = *(const float4*)(qs + j * 4);
      float4 kk;
      kk.x = ka.x + kb.x + bk + p.x; kk.y = ka.y + kb.y + bk + p.y;
      kk.z = ka.z + kb.z + bk + p.z; kk.w = ka.w + kb.w + bk + p.w;
      *(float4*)(dst + j * 4) = kk;
      part += q.x * kk.x + q.y * kk.y + q.z * kk.z + q.w * kk.w;
    }
  }
#pragma unroll
  for (int s = 32; s; s >>= 1) part += __shfl_xor(part, s);
  __shared__ float red[4];
  if (lane == 0) red[wid] = part;
  __syncthreads();
  if (t == 0)
    logits[((b << 3) + h) * 32 + m] = red[0] + red[1] + red[2] + red[3] + pb[m * 8 + h];
}

// ---------- attention V-pass: softmax + rv + attn out ----------
__global__ __launch_bounds__(256) void k_attnV(
    const float* __restrict__ kqvA, const float* __restrict__ kqvB,
    const float* __restrict__ projb, const int* __restrict__ mask,
    const float* __restrict__ cv, const float* __restrict__ logits,
    float* __restrict__ rv, float* __restrict__ attnb) {
  int bh = blockIdx.x, b = bh >> 3, h = bh & 7;
  int t = threadIdx.x;
  int d = (blockIdx.y << 10) + (t << 2);
  int hd = d >> 6, pix = d & 63;

  float lg[32];
#pragma unroll
  for (int j = 0; j < 8; ++j) {
    float4 v = *(const float4*)(logits + bh * 32 + j * 4);
    lg[j * 4 + 0] = v.x; lg[j * 4 + 1] = v.y; lg[j * 4 + 2] = v.z; lg[j * 4 + 3] = v.w;
  }
  float mx = -INFINITY;
#pragma unroll
  for (int m = 0; m < 32; ++m) {
    if (m == 31) lg[m] += 5.0f;
    else if (mask[bh * 32 + m] != 0) lg[m] = -INFINITY;
    mx = fmaxf(mx, lg[m]);
  }
  float sm = 0.f;
#pragma unroll
  for (int m = 0; m < 32; ++m) { lg[m] = __expf(lg[m] - mx); sm += lg[m]; }
  float rs = 1.f / sm;

  float4 acc = make_float4(0.f, 0.f, 0.f, 0.f);
  for (int m = 0; m < 31; ++m) {
    const float* src = cv + (((size_t)(b * 32 + m + 1) * 8 + h) << 12) + d;
    float4 v = *(const float4*)src;
    *(float4*)(rv + (((size_t)(b * 32 + m) * 8 + h) << 12) + d) = v;
    float wm = lg[m] * rs;
    acc.x += wm * v.x; acc.y += wm * v.y; acc.z += wm * v.z; acc.w += wm * v.w;
  }
  {
    size_t voff = ((size_t)(b * 1536 + 1024 + h * 64 + hd) << 6) + pix;
    float bv = projb[1024 + h * 64 + hd];
    float4 va = *(const float4*)(kqvA + voff);
    float4 vb = *(const float4*)(kqvB + voff);
    float4 v;
    v.x = va.x + vb.x + bv; v.y = va.y + vb.y + bv;
    v.z = va.z + vb.z + bv; v.w = va.w + vb.w + bv;
    *(float4*)(rv + (((size_t)(b * 32 + 31) * 8 + h) << 12) + d) = v;
    float wm = lg[31] * rs;
    acc.x += wm * v.x; acc.y += wm * v.y; acc.z += wm * v.z; acc.w += wm * v.w;
  }
  *(float4*)(attnb + ((size_t)(b * 512 + h * 64 + hd) << 6) + pix) = acc;
}

// ---------- LN stage 1: x = p0..p3 + resid + bias[ch]; write x + per-segment stats ----------
__global__ __launch_bounds__(256) void k_lnstat(
    const float* __restrict__ p, const float* __restrict__ resid,
    const float* __restrict__ bias, float* __restrict__ xbuf,
    float2* __restrict__ stat) {
  int bb = blockIdx.x, seg = blockIdx.y, t = threadIdx.x;
  int lane = t & 63, wid = t >> 6;
  size_t base = (size_t)bb << 15;
  float s = 0.f, sq = 0.f;
#pragma unroll
  for (int j = 0; j < 4; ++j) {
    int i = (seg << 12) + t * 4 + j * 1024;
    float4 v0 = *(const float4*)(p + base + i);
    float4 v1 = *(const float4*)(p + 2097152 + base + i);
    float4 v2 = *(const float4*)(p + 4194304 + base + i);
    float4 v3 = *(const float4*)(p + 6291456 + base + i);
    float4 vr = *(const float4*)(resid + base + i);
    float bs = bias[i >> 6];
    float4 xx;
    xx.x = v0.x + v1.x + v2.x + v3.x + vr.x + bs;
    xx.y = v0.y + v1.y + v2.y + v3.y + vr.y + bs;
    xx.z = v0.z + v1.z + v2.z + v3.z + vr.z + bs;
    xx.w = v0.w + v1.w + v2.w + v3.w + vr.w + bs;
    *(float4*)(xbuf + base + i) = xx;
    s += xx.x + xx.y + xx.z + xx.w;
    sq += xx.x * xx.x + xx.y * xx.y + xx.z * xx.z + xx.w * xx.w;
  }
#pragma unroll
  for (int k = 32; k; k >>= 1) { s += __shfl_xor(s, k); sq += __shfl_xor(sq, k); }
  __shared__ float rsm[4], rqm[4];
  if (lane == 0) { rsm[wid] = s; rqm[wid] = sq; }
  __syncthreads();
  if (t == 0)
    stat[bb * 8 + seg] = make_float2(rsm[0] + rsm[1] + rsm[2] + rsm[3],
                                     rqm[0] + rqm[1] + rqm[2] + rqm[3]);
}

// ---------- LN stage 2 (plain): normalize -> out ----------
__global__ __launch_bounds__(256) void k_lnapply(
    const float* __restrict__ xbuf, const float2* __restrict__ stat,
    const float* __restrict__ w, const float* __restrict__ beta,
    float* __restrict__ out) {
  int bb = blockIdx.x, seg = blockIdx.y, t = threadIdx.x;
  size_t base = (size_t)bb << 15;
  float s = 0.f, sq = 0.f;
#pragma unroll
  for (int k = 0; k < 8; ++k) {
    float2 st = stat[bb * 8 + k];
    s += st.x; sq += st.y;
  }
  float mean = s * (1.f / 32768.f);
  float var = sq * (1.f / 32768.f) - mean * mean;
  float rinv = rsqrtf(var + 1e-5f);
#pragma unroll
  for (int j = 0; j < 4; ++j) {
    int i = (seg << 12) + t * 4 + j * 1024;
    float4 xx = *(const float4*)(xbuf + base + i);
    float4 vw = *(const float4*)(w + i);
    float4 vt = *(const float4*)(beta + i);
    float4 r;
    r.x = (xx.x - mean) * rinv * vw.x + vt.x;
    r.y = (xx.y - mean) * rinv * vw.y + vt.y;
    r.z = (xx.z - mean) * rinv * vw.z + vt.z;
    r.w = (xx.w - mean) * rinv * vw.w + vt.w;
    *(float4*)(out + base + i) = r;
  }
}

// ---------- LN stage 2 fused with pad-transpose: normalize -> ln1 fp32 + l1pad bf16 ----------
__global__ __launch_bounds__(256) void k_lnpad(
    const float* __restrict__ xbuf, const float2* __restrict__ stat,
    const float* __restrict__ w, const float* __restrict__ beta,
    float* __restrict__ ln1, unsigned short* __restrict__ lp) {
  int b = blockIdx.x >> 3, c0 = (blockIdx.x & 7) << 6;
  int t = threadIdx.x;
  float s = 0.f, sq = 0.f;
#pragma unroll
  for (int k = 0; k < 8; ++k) {
    float2 st = stat[b * 8 + k];
    s += st.x; sq += st.y;
  }
  float mean = s * (1.f / 32768.f);
  float var = sq * (1.f / 32768.f) - mean * mean;
  float rinv = rsqrtf(var + 1e-5f);

  __shared__ float l[64][65];
  int cr = t >> 2, p0 = (t & 3) << 4;
  size_t off = ((size_t)b * 512 + c0 + cr) * 64 + p0;
  size_t woff = ((size_t)(c0 + cr)) * 64 + p0;
#pragma unroll
  for (int j = 0; j < 4; ++j) {
    float4 xx = *(const float4*)(xbuf + off + j * 4);
    float4 vw = *(const float4*)(w + woff + j * 4);
    float4 vt = *(const float4*)(beta + woff + j * 4);
    float4 r;
    r.x = (xx.x - mean) * rinv * vw.x + vt.x;
    r.y = (xx.y - mean) * rinv * vw.y + vt.y;
    r.z = (xx.z - mean) * rinv * vw.z + vt.z;
    r.w = (xx.w - mean) * rinv * vw.w + vt.w;
    *(float4*)(ln1 + off + j * 4) = r;
    l[cr][p0 + j * 4 + 0] = r.x; l[cr][p0 + j * 4 + 1] = r.y;
    l[cr][p0 + j * 4 + 2] = r.z; l[cr][p0 + j * 4 + 3] = r.w;
  }
  __syncthreads();
  int pix = t >> 2, cc0 = (t & 3) << 4;
  size_t prow = (size_t)b * 100 + 11 + (pix >> 3) * 10 + (pix & 7);
  unsigned short pk[16];
#pragma unroll
  for (int j = 0; j < 16; ++j) pk[j] = f2bf(l[cc0 + j][pix]);
  *(uint4*)(lp + prow * 512 + c0 + cc0) = *(const uint4*)pk;
  *(uint4*)(lp + prow * 512 + c0 + cc0 + 8) = *(const uint4*)(pk + 8);
}

extern "C" void kernel_launch(void* const* d_in, const int* in_sizes, int n_in,
                              void* d_out, int out_size, void* d_ws, size_t ws_size,
                              hipStream_t stream) {
  const float* x     = (const float*)d_in[0];
  const int*   mask  = (const int*)d_in[1];
  const float* ck    = (const float*)d_in[2];
  const float* cv    = (const float*)d_in[3];
  const float* projw = (const float*)d_in[4];
  const float* projb = (const float*)d_in[5];
  const float* outw  = (const float*)d_in[6];
  const float* outb  = (const float*)d_in[7];
  const float* l1w   = (const float*)d_in[8];
  const float* l1b   = (const float*)d_in[9];
  const float* l2w   = (const float*)d_in[10];
  const float* l2b   = (const float*)d_in[11];
  const float* n1w   = (const float*)d_in[12];
  const float* n1b   = (const float*)d_in[13];
  const float* n2w   = (const float*)d_in[14];
  const float* n2b   = (const float*)d_in[15];
  const float* posw  = (const float*)d_in[16];
  const float* posb  = (const float*)d_in[17];

  char* ws = (char*)d_ws;
  unsigned short* wbP   = (unsigned short*)(ws);             // 1536x4608
  unsigned short* wbO   = (unsigned short*)(ws + 14155776);  // 512x4608
  unsigned short* wbL1  = (unsigned short*)(ws + 18874368);  // 2048x4608
  unsigned short* wbL2  = (unsigned short*)(ws + 37748736);  // 512x18432
  unsigned short* xpadI = (unsigned short*)(ws + 56623104);  // 64x100x512
  unsigned short* apad  = (unsigned short*)(ws + 63176704);  // 64x100x512
  unsigned short* l1pad = (unsigned short*)(ws + 69730304);  // 64x100x512
  unsigned short* ffpad = (unsigned short*)(ws + 76283904);  // 64x100x2048
  float* kqvA   = (float*)(ws + 102498304);                  // proj partial z0
  float* kqvB   = (float*)(ws + 127664128);                  // proj partial z1
  float* qbuf   = (float*)(ws + 152829952);                  // 64x512x64 pre-scaled q
  float* logits = (float*)(ws + 177995776);                  // 512x32
  float* res    = (float*)(ws + 178061312);                  // 4 x 64x512x64 partials
  float* ln1    = (float*)(ws + 211615744);
  float* attnb  = (float*)(ws + 220004352);
  float* xbuf1  = (float*)(ws + 228392960);
  float* xbuf2  = (float*)(ws + 236781568);
  float2* stat1 = (float2*)(ws + 245170176);                 // 512 float2
  float2* stat2 = (float2*)(ws + 245174272);                 // ends ~245.2 MB

  float* out0 = (float*)d_out;
  float* rk = out0 + 2097152;
  float* rv = rk + 67108864;

  // merged border-zero + weight transforms + input pad
  k_prep<<<15872, 256, 0, stream>>>(projw, outw, l1w, l2w, x,
                                    wbP, wbO, wbL1, wbL2, xpadI, apad, l1pad, ffpad);

  // proj conv (split-K z=2) -> partials; q-slice sum (+bias, pre-scaled)
  k_gemm9<3><<<dim3(12, 32, 2), 256, 0, stream>>>(wbP, 4608, xpadI, 512, 3, 36, nullptr, kqvA, 1536, 6291456);
  k_sum2q<<<2048, 256, 0, stream>>>(kqvA, kqvB, projb, qbuf);

  // attention (full writes, q pre-summed; k/v slices from partials only at m==31)
  k_attnK<<<16384, 256, 0, stream>>>(qbuf, kqvA, kqvB, projb, ck, posw, posb, rk, logits);
  k_attnV<<<dim3(512, 4), 256, 0, stream>>>(kqvA, kqvB, projb, mask, cv, logits, rv, attnb);
  k_x2pad<<<512, 256, 0, stream>>>(attnb, apad);

  // out conv (split-K z=4) -> 4 partials; LN1 stats; fused LN1-apply + pad
  k_gemm9<3><<<dim3(4, 32, 4), 256, 0, stream>>>(wbO, 4608, apad, 512, 3, 18, nullptr, res, 512, 2097152);
  k_lnstat<<<dim3(64, 8), 256, 0, stream>>>(res, x, outb, xbuf1, stat1);
  k_lnpad<<<512, 256, 0, stream>>>(xbuf1, stat1, n1w, n1b, ln1, l1pad);

  // lin1 conv (+bias+relu) -> ffpad
  k_gemm9<4><<<dim3(16, 32, 1), 256, 0, stream>>>(wbL1, 4608, l1pad, 512, 3, 72, l1b, ffpad, 2048, 0);

  // lin2 conv (split-K z=4, 288 K-tiles) -> 4 partials; LN2 (+bias +ln1 residual) -> out
  k_gemm9<3><<<dim3(4, 32, 4), 256, 0, stream>>>(wbL2, 18432, ffpad, 2048, 5, 72, nullptr, res, 512, 2097152);
  k_lnstat<<<dim3(64, 8), 256, 0, stream>>>(res, ln1, l2b, xbuf2, stat2);
  k_lnapply<<<dim3(64, 8), 256, 0, stream>>>(xbuf2, stat2, n2w, n2b, out0);
}